// Round 7
// baseline (246.604 us; speedup 1.0000x reference)
//
#include <hip/hip_runtime.h>

// Triplet loss: mean(relu(|(a-p)W|^2 - |(a-n)W|^2 + 0.2)); bias cancels.
//
// R9 = R8 resubmitted verbatim (R6-round container death was infra:
// push_in_npz_s degraded 877->1099->1513s across passing rounds, and the
// kernel audits clean: no OOB, no deadlock, VGPR<=256, layout errors
// cancel by construction).
//
// R8 design: 32x32x16 MFMA => W amortized over M=32 AND 8 waves/CU.
// Session model (R2/R4/R6/R7): delivered vmem BW = f(waves/CU), capped
// ~5.6 TB/s aggregate (~22 GB/s/CU request-service cap); pipeline depth
// beyond ~1 chunk is irrelevant (R7 == R6). Frontier = min traffic
// (373 MB: 226 A/P/N + 147 W at M=32/block) x 8 waves/CU. 16x16 MFMA
// couldn't fit that in LDS (12KB/chunk/wave -> 192KB); 32x32x16 stages
// only K16 chunks: 6KB/chunk/wave -> 8 waves x 2 x 6KB = 96KB. Grid 256
// = 1 block/CU, K-split 8 (18 K16-chunks/wave), wave-private async DMA
// double-buffer, counted vmcnt(10) (= stage(c+1) 6 + W(c+1) 4, the only
// ops pinned younger than stage(c) by the asm memory fences ->
// placement-independent-safe, never drains prefetch).
//
// Layout (gfx950, mfma_f32_32x32x16_bf16):
//   A-frag: lane holds A[m=lane&31][k=(lane>>5)*8+j] (8 bf16) [slot->k
//     bijection cancels between A and B: both built identically]
//   B-frag: lane holds B[k=(lane>>5)*8+j][n=lane&31]
//   C/D:    lane holds D[row=(reg&3)+8*(reg>>2)+4*(lane>>5)][col=lane&31]
//     (m74/m101-verified; row-permutation errors cancel in the mean)

#define KDIM  2304   // 48*48
#define EMBD  128
#define BATCH 8192
#define NT    4      // 128 / 32 n-tiles
#define NW    8      // waves per block
#define CPW   18     // K16-chunks per wave: 144/8
#define ALPHA 0.2f

typedef __attribute__((ext_vector_type(8))) short short8;
typedef __attribute__((ext_vector_type(4))) float f32x4;
typedef __attribute__((ext_vector_type(16))) float f32x16;
typedef __attribute__((ext_vector_type(4))) unsigned int u32x4;

#define AS1 __attribute__((address_space(1)))
#define AS3 __attribute__((address_space(3)))

__device__ __forceinline__ unsigned short f2bf(float f) {
    unsigned u = __builtin_bit_cast(unsigned, f);
    u += 0x7FFFu + ((u >> 16) & 1u);       // round-to-nearest-even
    return (unsigned short)(u >> 16);
}

// Pack W for 32x32x16 B-fragments:
// Wp[((c*4 + t)*64 + l)*8 + j] = bf16(W[k][n]),
//   k = c*16 + (l>>5)*8 + j, n = t*32 + (l&31),  c = 0..143.
__global__ void pack_w_kernel(const float* __restrict__ W,
                              unsigned short* __restrict__ Wp) {
    int tid = blockIdx.x * blockDim.x + threadIdx.x;   // 0 .. 2304*128-1
    int n = tid & 127;
    int k = tid >> 7;
    int c = k >> 4;
    int q = (k >> 3) & 1;
    int j = k & 7;
    int t = n >> 5;
    int l = q * 32 + (n & 31);
    Wp[(size_t)(((c * 4 + t) * 64) + l) * 8 + j] = f2bf(W[tid]);
}

__device__ __forceinline__ unsigned cvtpk(float lo, float hi) {
    unsigned r;
    asm("v_cvt_pk_bf16_f32 %0, %1, %2" : "=v"(r) : "v"(lo), "v"(hi));
    return r;
}

// 16B/lane global->LDS DMA: LDS dest = uniform base + lane*16,
// global src per-lane (pre-swizzled into fragment order).
__device__ __forceinline__ void gll16(const float* g, char* l) {
    __builtin_amdgcn_global_load_lds((AS1 void*)(void*)g, (AS3 void*)l, 16, 0, 0);
}

// 6 fragment reads (a_j03,a_j47,p_j03,p_j47,n_j03,n_j47), one lgkmcnt(0).
// Outputs valid at block end (MFMA consumes them, data-dependent).
// "memory" clobber pins ordering vs global_load_lds buffer reuse.
__device__ __forceinline__ void lds_read6(const char* p, f32x4& a0, f32x4& a1,
                                          f32x4& p0, f32x4& p1,
                                          f32x4& n0, f32x4& n1) {
    const AS3 char* lp = (const AS3 char*)p;
    asm volatile(
        "ds_read_b128 %0, %6 offset:0\n\t"
        "ds_read_b128 %1, %6 offset:1024\n\t"
        "ds_read_b128 %2, %6 offset:2048\n\t"
        "ds_read_b128 %3, %6 offset:3072\n\t"
        "ds_read_b128 %4, %6 offset:4096\n\t"
        "ds_read_b128 %5, %6 offset:5120\n\t"
        "s_waitcnt lgkmcnt(0)"
        : "=&v"(a0), "=&v"(a1), "=&v"(p0), "=&v"(p1), "=&v"(n0), "=&v"(n1)
        : "v"(lp)
        : "memory");
}

__global__ __launch_bounds__(512, 2) void triplet_kernel(
    const float* __restrict__ A, const float* __restrict__ P,
    const float* __restrict__ Ng, const unsigned short* __restrict__ Wp,
    float* __restrict__ out)
{
    // 8 waves x (2 bufs x 6KB) staging = 96KB; reduce tree aliased after.
    __shared__ __align__(16) char smem[NW * 12288];

    const int lane = threadIdx.x & 63;
    const int wave = threadIdx.x >> 6;
    const int c0   = wave * CPW;             // this wave's first K16-chunk

    // Per-lane global base in fragment order:
    // row = blk*32 + (lane&31), k-base = (lane>>5)*8 floats; c0 folded in.
    const size_t goff = (size_t)(blockIdx.x * 32 + (lane & 31)) * KDIM
                      + (size_t)((lane >> 5) * 8) + (size_t)c0 * 16;
    const float* gA = A  + goff;
    const float* gP = P  + goff;
    const float* gN = Ng + goff;

    char* wb = smem + wave * 12288;          // wave-private staging

    // W fragments: short8 at ((cg*4 + t)*64 + lane), cg = c0 + c.
    const short8* wpw = (const short8*)Wp + lane + (size_t)c0 * 256;

    f32x16 aU[NT], aV[NT];
#pragma unroll
    for (int t = 0; t < NT; ++t) {
#pragma unroll
        for (int r = 0; r < 16; ++r) { aU[t][r] = 0.f; aV[t][r] = 0.f; }
    }

    // buf layout (6KB): A_j03 @0, A_j47 @1024, P @2048/3072, N @4096/5120
#define STAGE(cc, bufoff)                                   \
    do {                                                    \
        const int _o = (cc) * 16;                           \
        char* _b = wb + (bufoff);                           \
        gll16(gA + _o,     _b);                             \
        gll16(gA + _o + 4, _b + 1024);                      \
        gll16(gP + _o,     _b + 2048);                      \
        gll16(gP + _o + 4, _b + 3072);                      \
        gll16(gN + _o,     _b + 4096);                      \
        gll16(gN + _o + 4, _b + 5120);                      \
    } while (0)

#define LOADW(WF, cc)                                       \
    do {                                                    \
        _Pragma("unroll")                                   \
        for (int t = 0; t < NT; ++t)                        \
            WF[t] = wpw[(cc) * 256 + t * 64];               \
    } while (0)

#define COMPUTE(bufoff, WF)                                             \
    do {                                                                \
        f32x4 xa0, xa1, xp0, xp1, xn0, xn1;                             \
        lds_read6(wb + (bufoff) + lane * 16, xa0, xa1, xp0, xp1, xn0, xn1); \
        f32x4 ul = xa0 - xp0, uh = xa1 - xp1;                           \
        f32x4 vl = xa0 - xn0, vh = xa1 - xn1;                           \
        u32x4 uw, vw;                                                   \
        uw[0] = cvtpk(ul[0], ul[1]); uw[1] = cvtpk(ul[2], ul[3]);       \
        uw[2] = cvtpk(uh[0], uh[1]); uw[3] = cvtpk(uh[2], uh[3]);       \
        vw[0] = cvtpk(vl[0], vl[1]); vw[1] = cvtpk(vl[2], vl[3]);       \
        vw[2] = cvtpk(vh[0], vh[1]); vw[3] = cvtpk(vh[2], vh[3]);       \
        short8 uf = __builtin_bit_cast(short8, uw);                     \
        short8 vf = __builtin_bit_cast(short8, vw);                     \
        _Pragma("unroll")                                               \
        for (int t = 0; t < NT; ++t) {                                  \
            aU[t] = __builtin_amdgcn_mfma_f32_32x32x16_bf16(uf, WF[t], aU[t], 0, 0, 0); \
            aV[t] = __builtin_amdgcn_mfma_f32_32x32x16_bf16(vf, WF[t], aV[t], 0, 0, 0); \
        }                                                               \
    } while (0)

    short8 wf0[NT], wf1[NT];

    STAGE(0, 0);                             // prologue: chunk 0 -> buf0
    LOADW(wf0, 0);

    // Per iteration: issue stage(c+1)+W(c+1) (10 pinned ops), then
    // vmcnt(10): min ops younger than stage(c) = those 10 -> retires
    // stage(c) (and W(c) if scheduled after it) without ever draining
    // the prefetch. Tail drains once.
#pragma unroll
    for (int c = 0; c < CPW; ++c) {
        short8* wfc = (c & 1) ? wf1 : wf0;
        short8* wfn = (c & 1) ? wf0 : wf1;
        if (c + 1 < CPW) {
            STAGE(c + 1, ((c + 1) & 1) * 6144);
            LOADW(wfn, c + 1);
            asm volatile("s_waitcnt vmcnt(10)" ::: "memory");
        } else {
            asm volatile("s_waitcnt vmcnt(0)" ::: "memory");
        }
        COMPUTE((c & 1) * 6144, wfc);
    }

    __syncthreads();

    // ---- cross-wave C-fragment reduce: 8 -> 4 -> 2 -> 1, per array ----
    // Region r (r=0..3): [NT][64 lanes][16 floats] = 16 KB at smem+r*16384
    // (aliases staging, 64KB of 96KB). Two sequential trees (U then V)
    // keep the footprint at 4 regions.
#define STOREX(ACC, r)                                                  \
    do {                                                                \
        _Pragma("unroll")                                               \
        for (int t = 0; t < NT; ++t) {                                  \
            _Pragma("unroll")                                           \
            for (int q = 0; q < 4; ++q) {                               \
                f32x4 piece = {ACC[t][q*4+0], ACC[t][q*4+1],            \
                               ACC[t][q*4+2], ACC[t][q*4+3]};           \
                *(f32x4*)(smem + (r)*16384 + t*4096 + lane*64 + q*16) = piece; \
            }                                                           \
        }                                                               \
    } while (0)
#define ADDX(ACC, r)                                                    \
    do {                                                                \
        _Pragma("unroll")                                               \
        for (int t = 0; t < NT; ++t) {                                  \
            _Pragma("unroll")                                           \
            for (int q = 0; q < 4; ++q) {                               \
                f32x4 piece = *(const f32x4*)(smem + (r)*16384 + t*4096 + lane*64 + q*16); \
                ACC[t][q*4+0] += piece[0]; ACC[t][q*4+1] += piece[1];   \
                ACC[t][q*4+2] += piece[2]; ACC[t][q*4+3] += piece[3];   \
            }                                                           \
        }                                                               \
    } while (0)
#define TREE(ACC)                                                       \
    do {                                                                \
        if (wave >= 4) STOREX(ACC, wave - 4);                           \
        __syncthreads();                                                \
        if (wave < 4) ADDX(ACC, wave);                                  \
        __syncthreads();                                                \
        if (wave == 2 || wave == 3) STOREX(ACC, wave - 2);              \
        __syncthreads();                                                \
        if (wave < 2) ADDX(ACC, wave);                                  \
        __syncthreads();                                                \
        if (wave == 1) STOREX(ACC, 0);                                  \
        __syncthreads();                                                \
        if (wave == 0) ADDX(ACC, 0);                                    \
        __syncthreads();                                                \
    } while (0)

    TREE(aU);
    TREE(aV);

    if (wave == 0) {
        // Per-lane: 16 regs = 16 distinct rows (for this lane-half);
        // row = (r&3)+8*(r>>2)+4*(lane>>5), col = lane&31.
        float du[16], dv[16];
#pragma unroll
        for (int r = 0; r < 16; ++r) { du[r] = 0.f; dv[r] = 0.f; }
#pragma unroll
        for (int t = 0; t < NT; ++t)
#pragma unroll
            for (int r = 0; r < 16; ++r) {
                du[r] += aU[t][r] * aU[t][r];
                dv[r] += aV[t][r] * aV[t][r];
            }
        // reduce over the 32 cols (lanes sharing lane>>5)
#pragma unroll
        for (int msk = 1; msk < 32; msk <<= 1)
#pragma unroll
            for (int r = 0; r < 16; ++r) {
                du[r] += __shfl_xor(du[r], msk, 64);
                dv[r] += __shfl_xor(dv[r], msk, 64);
            }
        float s = 0.f;
#pragma unroll
        for (int r = 0; r < 16; ++r) {
            float l = du[r] - dv[r] + ALPHA;
            s += l > 0.f ? l : 0.f;
        }
        s += __shfl_xor(s, 32, 64);          // other lane-half's 16 rows
        if (lane == 0) atomicAdd(out, s * (1.0f / BATCH));
    }
}

extern "C" void kernel_launch(void* const* d_in, const int* in_sizes, int n_in,
                              void* d_out, int out_size, void* d_ws, size_t ws_size,
                              hipStream_t stream) {
    const float* A  = (const float*)d_in[0];
    const float* P  = (const float*)d_in[1];
    const float* Ng = (const float*)d_in[2];
    const float* W  = (const float*)d_in[3];
    unsigned short* Wp = (unsigned short*)d_ws;   // 144*4*64*8 bf16 = 589,824 B

    hipMemsetAsync(d_out, 0, sizeof(float), stream);

    pack_w_kernel<<<(KDIM * EMBD) / 256, 256, 0, stream>>>(W, Wp);
    triplet_kernel<<<BATCH / 32, 512, 0, stream>>>(A, P, Ng, Wp, (float*)d_out);
}